// Round 14
// baseline (118.531 us; speedup 1.0000x reference)
//
#include <hip/hip_runtime.h>
#include <hip/hip_bf16.h>
#include <cstdint>
#include <cstddef>

#define DEVI static __device__ __forceinline__

typedef short s16x8 __attribute__((ext_vector_type(8)));
typedef float f32x4 __attribute__((ext_vector_type(4)));
typedef float f32x16 __attribute__((ext_vector_type(16)));
typedef unsigned u32x4 __attribute__((ext_vector_type(4)));

DEVI f32x4 mfma16x16(s16x8 a, s16x8 b, f32x4 c) {
  return __builtin_amdgcn_mfma_f32_16x16x32_bf16(a, b, c, 0, 0, 0);
}
DEVI f32x16 mfma32x32(s16x8 a, s16x8 b, f32x16 c) {
  return __builtin_amdgcn_mfma_f32_32x32x16_bf16(a, b, c, 0, 0, 0);
}

// HW float->bf16
DEVI unsigned short hcvt(float f) {
  return __builtin_bit_cast(unsigned short, __float2bfloat16(f));
}
// packed cvt: dst[15:0]=bf16(a), dst[31:16]=bf16(b)
DEVI unsigned cvtpk(float a, float b) {
  unsigned r;
  asm("v_cvt_pk_bf16_f32 %0, %1, %2" : "=v"(r) : "v"(a), "v"(b));
  return r;
}

DEVI s16x8 ld8(const unsigned short* p) { return *(const s16x8*)p; }

// async global->LDS, 16B per lane; dest = wave-uniform base + lane*16
DEVI void gload16(const void* g, void* l) {
  __builtin_amdgcn_global_load_lds(
      (const __attribute__((address_space(1))) void*)g,
      (__attribute__((address_space(3))) void*)l, 16, 0, 0);
}

// ---------------------------------------------------------------------------
// fused fp32 -> bf16 bulk convert of all three inputs (one launch)
// ---------------------------------------------------------------------------
__global__ __launch_bounds__(256) void cvt_all(
    const float* __restrict__ x, const float* __restrict__ w1,
    const float* __restrict__ w2, unsigned short* __restrict__ Xb,
    unsigned short* __restrict__ Wb, unsigned short* __restrict__ Wob) {
  int i = blockIdx.x * 256 + threadIdx.x;   // [0, 1048576)
  const float* s;
  unsigned short* d;
  int off;
  if (i < 524288) { s = x; d = Xb; off = i; }
  else if (i < 917504) { s = w1; d = Wb; off = i - 524288; }
  else { s = w2; d = Wob; off = i - 917504; }
  const float4* sp = (const float4*)s + (size_t)off * 2;
  float4 a = sp[0], b = sp[1];
  s16x8 r;
  r[0] = (short)hcvt(a.x); r[1] = (short)hcvt(a.y);
  r[2] = (short)hcvt(a.z); r[3] = (short)hcvt(a.w);
  r[4] = (short)hcvt(b.x); r[5] = (short)hcvt(b.y);
  r[6] = (short)hcvt(b.z); r[7] = (short)hcvt(b.w);
  *(s16x8*)(d + (size_t)off * 8) = r;
}

// ---------------------------------------------------------------------------
// GEMM1: C[m][n] = sum_k A[m][k]*B[n][k], 128x128x64 tiles, global_load_lds
// staging (m97 loop, pre-swizzled source chunk), fused qkv/RoPE epilogue.
// XCD-chunked block swizzle; 3 blocks/CU (one dispatch round for 768 blocks).
// ---------------------------------------------------------------------------
__global__ __launch_bounds__(256, 3) void gemm_qkv(
    const unsigned short* __restrict__ A, const unsigned short* __restrict__ B,
    unsigned short* __restrict__ Qp, unsigned short* __restrict__ Kp,
    unsigned short* __restrict__ Vp, int M, int N, int K) {
  __shared__ __align__(16) unsigned short As[128 * 64];
  __shared__ __align__(16) unsigned short Bs[128 * 64];
  const int tid = threadIdx.x;
  const int lin = blockIdx.y * 24 + blockIdx.x;       // 0..767
  const int swz = (lin & 7) * 96 + (lin >> 3);        // XCD-chunked, bijective
  const int m0 = (swz / 24) * 128, n0 = (swz % 24) * 128;
  const int wid = tid >> 6, lane = tid & 63;
  const int wm = wid >> 1, wn = wid & 1;
  const int lr = lane & 15, lg = lane >> 4;

  f32x4 acc[4][4] = {};
  const int T = K >> 6;

  for (int t = 0; t < T; ++t) {
    const int k0 = t << 6;
    __syncthreads();
    #pragma unroll
    for (int j = 0; j < 4; ++j) {
      const int c = j * 256 + tid;
      const int row = c >> 3;
      const int ck = (c & 7) ^ (row & 7);
      gload16(A + (size_t)(m0 + row) * K + k0 + ck * 8,
              &As[(j * 256 + (tid & 192)) * 8]);
      gload16(B + (size_t)(n0 + row) * K + k0 + ck * 8,
              &Bs[(j * 256 + (tid & 192)) * 8]);
    }
    asm volatile("s_waitcnt vmcnt(0)" ::: "memory");
    __syncthreads();
    s16x8 af[4][2], bf[4][2];
    #pragma unroll
    for (int m = 0; m < 4; ++m)
      #pragma unroll
      for (int kk = 0; kk < 2; ++kk) {
        int row = wm * 64 + m * 16 + lr;
        af[m][kk] = *(const s16x8*)&As[row * 64 + ((kk * 32 + lg * 8) ^ ((row & 7) << 3))];
      }
    #pragma unroll
    for (int n = 0; n < 4; ++n)
      #pragma unroll
      for (int kk = 0; kk < 2; ++kk) {
        int row = wn * 64 + n * 16 + lr;
        bf[n][kk] = *(const s16x8*)&Bs[row * 64 + ((kk * 32 + lg * 8) ^ ((row & 7) << 3))];
      }
    #pragma unroll
    for (int kk = 0; kk < 2; ++kk)
      #pragma unroll
      for (int m = 0; m < 4; ++m)
        #pragma unroll
        for (int n = 0; n < 4; ++n)
          acc[m][n] = mfma16x16(af[m][kk], bf[n][kk], acc[m][n]);
  }

  // fused qkv split + RoPE epilogue (C/D layout: row = lg*4+i, col = lr)
  const int colb = n0 + wn * 64;          // wave's 64-col span = one head
  const int part = colb >> 10;            // 0=q 1=k 2=v (block-uniform)
  const int h = (colb & 1023) >> 6;
  #pragma unroll
  for (int m = 0; m < 4; ++m)
    #pragma unroll
    for (int i = 0; i < 4; ++i) {
      const int r = m0 + wm * 64 + m * 16 + lg * 4 + i;
      const int b = r >> 11, s = r & 2047;
      const size_t bh = (size_t)b * 16 + h;
      if (part == 2) {
        #pragma unroll
        for (int n = 0; n < 4; ++n)
          Vp[(bh * 64 + n * 16 + lr) * 2048 + s] = hcvt(acc[m][n][i]);
      } else {
        #pragma unroll
        for (int n = 0; n < 2; ++n) {
          const int d = n * 16 + lr;      // 0..31; pair (d, d+32) in-lane
          float ang = (float)s * exp2f((float)d * -0.4152410118609203f);
          float c = __cosf(ang), sn = __sinf(ang);
          float x1 = acc[m][n][i], x2 = acc[m][n + 2][i];
          float o1 = x1 * c - x2 * sn;
          float o2 = x2 * c + x1 * sn;
          unsigned short* dst;
          if (part == 0) {
            // fold 1/sqrt(dh) AND log2(e) so attention can use exp2
            o1 *= 0.18033688f; o2 *= 0.18033688f; dst = Qp;
          } else dst = Kp;
          dst[(bh * 2048 + s) * 64 + d] = hcvt(o1);
          dst[(bh * 2048 + s) * 64 + d + 32] = hcvt(o2);
        }
      }
    }
}

// ---------------------------------------------------------------------------
// GEMM3: 128x64 tiles (2 blocks/CU), global_load_lds staging, fp32 out.
// ---------------------------------------------------------------------------
__global__ __launch_bounds__(256, 2) void gemm_out(
    const unsigned short* __restrict__ A, const unsigned short* __restrict__ B,
    float* __restrict__ Cf, int M, int N, int K) {
  __shared__ __align__(16) unsigned short As[128 * 64];
  __shared__ __align__(16) unsigned short Bs[64 * 64];
  const int tid = threadIdx.x;
  const int lin = blockIdx.y * 16 + blockIdx.x;       // 0..511
  const int swz = (lin & 7) * 64 + (lin >> 3);        // XCD-chunked, bijective
  const int m0 = (swz >> 4) * 128, n0 = (swz & 15) * 64;
  const int wid = tid >> 6, lane = tid & 63;
  const int lr = lane & 15, lg = lane >> 4;

  f32x4 acc[2][4] = {};
  const int T = K >> 6;

  for (int t = 0; t < T; ++t) {
    const int k0 = t << 6;
    __syncthreads();
    #pragma unroll
    for (int j = 0; j < 4; ++j) {
      const int c = j * 256 + tid;
      const int row = c >> 3;
      const int ck = (c & 7) ^ (row & 7);
      gload16(A + (size_t)(m0 + row) * K + k0 + ck * 8,
              &As[(j * 256 + (tid & 192)) * 8]);
    }
    #pragma unroll
    for (int j = 0; j < 2; ++j) {
      const int c = j * 256 + tid;
      const int row = c >> 3;
      const int ck = (c & 7) ^ (row & 7);
      gload16(B + (size_t)(n0 + row) * K + k0 + ck * 8,
              &Bs[(j * 256 + (tid & 192)) * 8]);
    }
    asm volatile("s_waitcnt vmcnt(0)" ::: "memory");
    __syncthreads();
    s16x8 af[2][2], bf[4][2];
    #pragma unroll
    for (int m = 0; m < 2; ++m)
      #pragma unroll
      for (int kk = 0; kk < 2; ++kk) {
        int row = wid * 32 + m * 16 + lr;
        af[m][kk] = *(const s16x8*)&As[row * 64 + ((kk * 32 + lg * 8) ^ ((row & 7) << 3))];
      }
    #pragma unroll
    for (int n = 0; n < 4; ++n)
      #pragma unroll
      for (int kk = 0; kk < 2; ++kk) {
        int row = n * 16 + lr;
        bf[n][kk] = *(const s16x8*)&Bs[row * 64 + ((kk * 32 + lg * 8) ^ ((row & 7) << 3))];
      }
    #pragma unroll
    for (int kk = 0; kk < 2; ++kk)
      #pragma unroll
      for (int m = 0; m < 2; ++m)
        #pragma unroll
        for (int n = 0; n < 4; ++n)
          acc[m][n] = mfma16x16(af[m][kk], bf[n][kk], acc[m][n]);
  }

  #pragma unroll
  for (int m = 0; m < 2; ++m)
    #pragma unroll
    for (int i = 0; i < 4; ++i) {
      int r = m0 + wid * 32 + m * 16 + lg * 4 + i;
      #pragma unroll
      for (int n = 0; n < 4; ++n)
        Cf[(size_t)r * N + n0 + n * 16 + lr] = acc[m][n][i];
    }
}

// ---------------------------------------------------------------------------
// Causal flash attention — 32x32x16 MFMA: ONE wave covers 32 q-rows with the
// SAME 16 ds_read_b128 per KV tile (per-q LDS traffic halved vs r9/r13).
// C/D layout (HW-verified m74/m101): col=lane&31 (q), row=(reg&3)+8*(reg>>2)
// +4*(lane>>5) (kv). K rows staged with sigma = swap-bits-2-3 of the row
// index, chosen so the QK C-slot enumeration equals the PV B-operand slot
// enumeration: pf[s] = pack(e[kv-half s>>1][regs 8*(s&1)..+7]) feeds PV
// directly from registers (zero-shuffle PV). V staged naturally.
// Mask per slot: kv_local = 16*((reg>>3)&1) + 8*hi + 4*((reg>>2)&1) +
// (reg&3) (+32 for half 1). Max-free softmax (r9-verified exact).
// Block: 2 waves x 32 q = 64-row tile; pair (p,31-p) -> uniform 33 iters.
// 512 blocks (XCD-chunked) = 2 blocks/CU.
// Qr/Kr: bf16 [BH][S][64] (Q pre-scaled by log2e/8), VT: bf16 [BH][64][S].
// ---------------------------------------------------------------------------
__global__ __launch_bounds__(128, 1) void attn_fwd(
    const unsigned short* __restrict__ Qr, const unsigned short* __restrict__ Kr,
    const unsigned short* __restrict__ VT, unsigned short* __restrict__ Z) {
  __shared__ __align__(16) unsigned short Kl[2][64 * 64];
  __shared__ __align__(16) unsigned short Vl[2][64 * 64];
  const int tid = threadIdx.x;
  const int orig = blockIdx.x;
  const int bid = (orig & 7) * 64 + (orig >> 3);    // XCD-chunked, bijective
  const int bh = bid >> 4, p = bid & 15;
  const int b = bh >> 4, h = bh & 15;
  const int wid = tid >> 6, lane = tid & 63;
  const int lq = lane & 31, hi = lane >> 5;

  const unsigned short* Qb = Qr + ((size_t)bh << 17);
  const unsigned short* Kb = Kr + ((size_t)bh << 17);
  const unsigned short* Vb = VT + ((size_t)bh << 17);

  // staging (128 threads): unit u = j*128 + tid -> row u>>3, chunk u&7
  auto STAGE = [&](int buf, int t2) {
    const int kv = t2 << 6;
    #pragma unroll
    for (int j = 0; j < 4; ++j) {
      const int u = j * 128 + tid;
      const int row = u >> 3;
      const int ck = (u & 7) ^ (row & 7);           // pre-swizzled source chunk
      const int sig = (row & ~12) | ((row & 4) << 1) | ((row & 8) >> 1); // swap b2,b3
      gload16(Kb + (size_t)(kv + sig) * 64 + ck * 8,
              &Kl[buf][(j * 128 + (tid & 64)) * 8]);
      gload16(Vb + (size_t)row * 2048 + kv + ck * 8,
              &Vl[buf][(j * 128 + (tid & 64)) * 8]);
    }
  };

  for (int side = 0; side < 2; ++side) {
    const int qt = side ? (31 - p) : p;     // 64-row q-tile index
    const int qw = (qt << 6) + (wid << 5);  // wave's 32 q rows
    const int qme = qw + lq;                // THE q-row this lane owns
    const int nt = qt + 1;                  // KV tiles 0..qt

    s16x8 qf[4];                            // B-frag: col=q, k = s4*16+hi*8+j
    #pragma unroll
    for (int s4 = 0; s4 < 4; ++s4)
      qf[s4] = ld8(Qb + (size_t)qme * 64 + s4 * 16 + hi * 8);

    f32x16 o0 = {}, o1 = {};                // O^T[d][q], d-halves 0..31/32..63
    float lsum = 0.f;                       // per-lane partial row sum

    STAGE(0, 0);
    asm volatile("s_waitcnt vmcnt(0)" ::: "memory");
    __syncthreads();
    int cur = 0;

    const int R0 = lq, R1 = 32 + lq;
    const int sw = (lq & 7) << 3;           // R0&7 == R1&7

    for (int t = 0; t < nt; ++t) {
      const int kv0 = t << 6;
      if (t + 1 < nt) STAGE(cur ^ 1, t + 1);   // overlaps all compute below

      // QK: S^T[kv][q] for both 32-row kv halves (A=K rows, B=Q)
      f32x16 s0 = {}, s1 = {};
      #pragma unroll
      for (int s4 = 0; s4 < 4; ++s4) {
        const int off = (s4 * 16 + hi * 8) ^ sw;
        s16x8 k0 = *(const s16x8*)&Kl[cur][R0 * 64 + off];
        s16x8 k1 = *(const s16x8*)&Kl[cur][R1 * 64 + off];
        s0 = mfma32x32(k0, qf[s4], s0);
        s1 = mfma32x32(k1, qf[s4], s1);
      }

      // causal mask (diagonal tile only), sigma-mapped kv per C-slot
      if (t == nt - 1) {
        #pragma unroll
        for (int reg = 0; reg < 16; ++reg) {
          const int kb = 16 * ((reg >> 3) & 1) + 8 * hi +
                         4 * ((reg >> 2) & 1) + (reg & 3);
          if (kv0 + kb > qme) s0[reg] = -__builtin_inff();
          if (kv0 + 32 + kb > qme) s1[reg] = -__builtin_inff();
        }
      }

      // e = exp2(S) (max-free), per-lane partial sum
      #pragma unroll
      for (int reg = 0; reg < 16; ++reg) {
        s0[reg] = __builtin_amdgcn_exp2f(s0[reg]);
        s1[reg] = __builtin_amdgcn_exp2f(s1[reg]);
        lsum += s0[reg] + s1[reg];
      }

      // P B-frags in registers: pf[s][j] = e[s>>1][(s&1)*8 + j]
      u32x4 w0, w1, w2, w3;
      w0[0] = cvtpk(s0[0], s0[1]);   w0[1] = cvtpk(s0[2], s0[3]);
      w0[2] = cvtpk(s0[4], s0[5]);   w0[3] = cvtpk(s0[6], s0[7]);
      w1[0] = cvtpk(s0[8], s0[9]);   w1[1] = cvtpk(s0[10], s0[11]);
      w1[2] = cvtpk(s0[12], s0[13]); w1[3] = cvtpk(s0[14], s0[15]);
      w2[0] = cvtpk(s1[0], s1[1]);   w2[1] = cvtpk(s1[2], s1[3]);
      w2[2] = cvtpk(s1[4], s1[5]);   w2[3] = cvtpk(s1[6], s1[7]);
      w3[0] = cvtpk(s1[8], s1[9]);   w3[1] = cvtpk(s1[10], s1[11]);
      w3[2] = cvtpk(s1[12], s1[13]); w3[3] = cvtpk(s1[14], s1[15]);
      const s16x8 pf0 = __builtin_bit_cast(s16x8, w0);
      const s16x8 pf1 = __builtin_bit_cast(s16x8, w1);
      const s16x8 pf2 = __builtin_bit_cast(s16x8, w2);
      const s16x8 pf3 = __builtin_bit_cast(s16x8, w3);

      // PV: O^T += V^T P^T (A=V^T rows d, B=P; V natural order)
      {
        const int off = (hi * 8) ^ sw;                  // s=0
        s16x8 v0 = *(const s16x8*)&Vl[cur][R0 * 64 + off];
        s16x8 v1 = *(const s16x8*)&Vl[cur][R1 * 64 + off];
        o0 = mfma32x32(v0, pf0, o0);
        o1 = mfma32x32(v1, pf0, o1);
      }
      {
        const int off = (16 + hi * 8) ^ sw;             // s=1
        s16x8 v0 = *(const s16x8*)&Vl[cur][R0 * 64 + off];
        s16x8 v1 = *(const s16x8*)&Vl[cur][R1 * 64 + off];
        o0 = mfma32x32(v0, pf1, o0);
        o1 = mfma32x32(v1, pf1, o1);
      }
      {
        const int off = (32 + hi * 8) ^ sw;             // s=2
        s16x8 v0 = *(const s16x8*)&Vl[cur][R0 * 64 + off];
        s16x8 v1 = *(const s16x8*)&Vl[cur][R1 * 64 + off];
        o0 = mfma32x32(v0, pf2, o0);
        o1 = mfma32x32(v1, pf2, o1);
      }
      {
        const int off = (48 + hi * 8) ^ sw;             // s=3
        s16x8 v0 = *(const s16x8*)&Vl[cur][R0 * 64 + off];
        s16x8 v1 = *(const s16x8*)&Vl[cur][R1 * 64 + off];
        o0 = mfma32x32(v0, pf3, o0);
        o1 = mfma32x32(v1, pf3, o1);
      }

      // next tile's loads done + everyone finished reading buf cur
      asm volatile("s_waitcnt vmcnt(0)" ::: "memory");
      __syncthreads();
      cur ^= 1;
    }

    // row sum: lanes l and l^32 share q; normalize + write Z
    float ltot = lsum + __shfl_xor(lsum, 32);
    const float inv = 1.f / ltot;
    // d = dh*32 + (reg&3) + 8*(reg>>2) + 4*hi
    const size_t base = ((size_t)b * 2048 + qme) * 1024 + h * 64 + hi * 4;
    #pragma unroll
    for (int g = 0; g < 4; ++g) {
      uint2 ua, ub;
      ua.x = cvtpk(o0[4 * g + 0] * inv, o0[4 * g + 1] * inv);
      ua.y = cvtpk(o0[4 * g + 2] * inv, o0[4 * g + 3] * inv);
      ub.x = cvtpk(o1[4 * g + 0] * inv, o1[4 * g + 1] * inv);
      ub.y = cvtpk(o1[4 * g + 2] * inv, o1[4 * g + 3] * inv);
      *(uint2*)&Z[base + 8 * g] = ua;
      *(uint2*)&Z[base + 32 + 8 * g] = ub;
    }
  }
}

// ---------------------------------------------------------------------------
extern "C" void kernel_launch(void* const* d_in, const int* in_sizes, int n_in,
                              void* d_out, int out_size, void* d_ws, size_t ws_size,
                              hipStream_t stream) {
  const float* x     = (const float*)d_in[0];   // [2,2048,1024]
  const float* w_qkv = (const float*)d_in[1];   // [3072,1024]
  const float* w_o   = (const float*)d_in[2];   // [1024,1024]
  float* out = (float*)d_out;                   // [2,2048,1024] fp32

  unsigned short* wsp = (unsigned short*)d_ws;
  unsigned short* Qr  = wsp;                    // [32][2048][64] bf16  (8 MB)
  unsigned short* Kr  = wsp + 4194304;          // [32][2048][64] bf16  (8 MB)
  unsigned short* VT  = wsp + 8388608;          // [32][64][2048] bf16  (8 MB)
  unsigned short* Xb  = wsp + 12582912;         // [4096][1024]  bf16   (8 MB)
  unsigned short* Z   = Xb;                     // aliases Xb (disjoint lifetime)
  unsigned short* Wb  = wsp + 16777216;         // [3072][1024]  bf16   (6 MB)
  unsigned short* Wob = wsp + 19922944;         // [1024][1024]  bf16   (2 MB)
  // total ws use: 40 MiB

  // 0) fused one-time fp32 -> bf16 conversions
  cvt_all<<<4096, 256, 0, stream>>>(x, w_qkv, w_o, Xb, Wb, Wob);

  // 1) QKV projection (global_load_lds staging, 3 blocks/CU) + RoPE epilogue
  gemm_qkv<<<dim3(24, 32), 256, 0, stream>>>(
      Xb, Wb, Qr, Kr, VT, 4096, 3072, 1024);

  // 2) causal flash attention (32x32 MFMA, 32 q/wave, max-free softmax)
  attn_fwd<<<512, 128, 0, stream>>>(Qr, Kr, VT, Z);

  // 3) output projection (128x64 tiles, 2 blocks/CU) (fp32 out)
  gemm_out<<<dim3(16, 32), 256, 0, stream>>>(
      Z, Wob, out, 4096, 1024, 1024);
}

// Round 15
// 99.495 us; speedup vs baseline: 1.1913x; 1.1913x over previous
//
#include <hip/hip_runtime.h>
#include <hip/hip_bf16.h>
#include <cstdint>
#include <cstddef>

#define DEVI static __device__ __forceinline__

typedef short s16x8 __attribute__((ext_vector_type(8)));
typedef float f32x4 __attribute__((ext_vector_type(4)));
typedef unsigned u32x4 __attribute__((ext_vector_type(4)));

DEVI f32x4 mfma16x16(s16x8 a, s16x8 b, f32x4 c) {
  return __builtin_amdgcn_mfma_f32_16x16x32_bf16(a, b, c, 0, 0, 0);
}

// HW float->bf16
DEVI unsigned short hcvt(float f) {
  return __builtin_bit_cast(unsigned short, __float2bfloat16(f));
}
// packed cvt: dst[15:0]=bf16(a), dst[31:16]=bf16(b)
DEVI unsigned cvtpk(float a, float b) {
  unsigned r;
  asm("v_cvt_pk_bf16_f32 %0, %1, %2" : "=v"(r) : "v"(a), "v"(b));
  return r;
}

DEVI s16x8 ld8(const unsigned short* p) { return *(const s16x8*)p; }

// async global->LDS, 16B per lane; dest = wave-uniform base + lane*16
DEVI void gload16(const void* g, void* l) {
  __builtin_amdgcn_global_load_lds(
      (const __attribute__((address_space(1))) void*)g,
      (__attribute__((address_space(3))) void*)l, 16, 0, 0);
}

// ---------------------------------------------------------------------------
// fused fp32 -> bf16 bulk convert of all three inputs (one launch)
// ---------------------------------------------------------------------------
__global__ __launch_bounds__(256) void cvt_all(
    const float* __restrict__ x, const float* __restrict__ w1,
    const float* __restrict__ w2, unsigned short* __restrict__ Xb,
    unsigned short* __restrict__ Wb, unsigned short* __restrict__ Wob) {
  int i = blockIdx.x * 256 + threadIdx.x;   // [0, 1048576)
  const float* s;
  unsigned short* d;
  int off;
  if (i < 524288) { s = x; d = Xb; off = i; }
  else if (i < 917504) { s = w1; d = Wb; off = i - 524288; }
  else { s = w2; d = Wob; off = i - 917504; }
  const float4* sp = (const float4*)s + (size_t)off * 2;
  float4 a = sp[0], b = sp[1];
  s16x8 r;
  r[0] = (short)hcvt(a.x); r[1] = (short)hcvt(a.y);
  r[2] = (short)hcvt(a.z); r[3] = (short)hcvt(a.w);
  r[4] = (short)hcvt(b.x); r[5] = (short)hcvt(b.y);
  r[6] = (short)hcvt(b.z); r[7] = (short)hcvt(b.w);
  *(s16x8*)(d + (size_t)off * 8) = r;
}

// ---------------------------------------------------------------------------
// GEMM1: C[m][n] = sum_k A[m][k]*B[n][k], 128x128x64 tiles, global_load_lds
// staging (m97 loop, pre-swizzled source chunk), fused qkv/RoPE epilogue.
// XCD-chunked block swizzle; 3 blocks/CU (one dispatch round for 768 blocks).
// ---------------------------------------------------------------------------
__global__ __launch_bounds__(256, 3) void gemm_qkv(
    const unsigned short* __restrict__ A, const unsigned short* __restrict__ B,
    unsigned short* __restrict__ Qp, unsigned short* __restrict__ Kp,
    unsigned short* __restrict__ Vp, int M, int N, int K) {
  __shared__ __align__(16) unsigned short As[128 * 64];
  __shared__ __align__(16) unsigned short Bs[128 * 64];
  const int tid = threadIdx.x;
  const int lin = blockIdx.y * 24 + blockIdx.x;       // 0..767
  const int swz = (lin & 7) * 96 + (lin >> 3);        // XCD-chunked, bijective
  const int m0 = (swz / 24) * 128, n0 = (swz % 24) * 128;
  const int wid = tid >> 6, lane = tid & 63;
  const int wm = wid >> 1, wn = wid & 1;
  const int lr = lane & 15, lg = lane >> 4;

  f32x4 acc[4][4] = {};
  const int T = K >> 6;

  for (int t = 0; t < T; ++t) {
    const int k0 = t << 6;
    __syncthreads();
    #pragma unroll
    for (int j = 0; j < 4; ++j) {
      const int c = j * 256 + tid;
      const int row = c >> 3;
      const int ck = (c & 7) ^ (row & 7);
      gload16(A + (size_t)(m0 + row) * K + k0 + ck * 8,
              &As[(j * 256 + (tid & 192)) * 8]);
      gload16(B + (size_t)(n0 + row) * K + k0 + ck * 8,
              &Bs[(j * 256 + (tid & 192)) * 8]);
    }
    asm volatile("s_waitcnt vmcnt(0)" ::: "memory");
    __syncthreads();
    s16x8 af[4][2], bf[4][2];
    #pragma unroll
    for (int m = 0; m < 4; ++m)
      #pragma unroll
      for (int kk = 0; kk < 2; ++kk) {
        int row = wm * 64 + m * 16 + lr;
        af[m][kk] = *(const s16x8*)&As[row * 64 + ((kk * 32 + lg * 8) ^ ((row & 7) << 3))];
      }
    #pragma unroll
    for (int n = 0; n < 4; ++n)
      #pragma unroll
      for (int kk = 0; kk < 2; ++kk) {
        int row = wn * 64 + n * 16 + lr;
        bf[n][kk] = *(const s16x8*)&Bs[row * 64 + ((kk * 32 + lg * 8) ^ ((row & 7) << 3))];
      }
    #pragma unroll
    for (int kk = 0; kk < 2; ++kk)
      #pragma unroll
      for (int m = 0; m < 4; ++m)
        #pragma unroll
        for (int n = 0; n < 4; ++n)
          acc[m][n] = mfma16x16(af[m][kk], bf[n][kk], acc[m][n]);
  }

  // fused qkv split + RoPE epilogue (C/D layout: row = lg*4+i, col = lr)
  const int colb = n0 + wn * 64;          // wave's 64-col span = one head
  const int part = colb >> 10;            // 0=q 1=k 2=v (block-uniform)
  const int h = (colb & 1023) >> 6;
  #pragma unroll
  for (int m = 0; m < 4; ++m)
    #pragma unroll
    for (int i = 0; i < 4; ++i) {
      const int r = m0 + wm * 64 + m * 16 + lg * 4 + i;
      const int b = r >> 11, s = r & 2047;
      const size_t bh = (size_t)b * 16 + h;
      if (part == 2) {
        #pragma unroll
        for (int n = 0; n < 4; ++n)
          Vp[(bh * 64 + n * 16 + lr) * 2048 + s] = hcvt(acc[m][n][i]);
      } else {
        #pragma unroll
        for (int n = 0; n < 2; ++n) {
          const int d = n * 16 + lr;      // 0..31; pair (d, d+32) in-lane
          float ang = (float)s * exp2f((float)d * -0.4152410118609203f);
          float c = __cosf(ang), sn = __sinf(ang);
          float x1 = acc[m][n][i], x2 = acc[m][n + 2][i];
          float o1 = x1 * c - x2 * sn;
          float o2 = x2 * c + x1 * sn;
          unsigned short* dst;
          if (part == 0) {
            // fold 1/sqrt(dh) AND log2(e) so attention can use exp2
            o1 *= 0.18033688f; o2 *= 0.18033688f; dst = Qp;
          } else dst = Kp;
          dst[(bh * 2048 + s) * 64 + d] = hcvt(o1);
          dst[(bh * 2048 + s) * 64 + d + 32] = hcvt(o2);
        }
      }
    }
}

// ---------------------------------------------------------------------------
// GEMM3: 128x64 tiles (2 blocks/CU), global_load_lds staging, fp32 out.
// ---------------------------------------------------------------------------
__global__ __launch_bounds__(256, 2) void gemm_out(
    const unsigned short* __restrict__ A, const unsigned short* __restrict__ B,
    float* __restrict__ Cf, int M, int N, int K) {
  __shared__ __align__(16) unsigned short As[128 * 64];
  __shared__ __align__(16) unsigned short Bs[64 * 64];
  const int tid = threadIdx.x;
  const int lin = blockIdx.y * 16 + blockIdx.x;       // 0..511
  const int swz = (lin & 7) * 64 + (lin >> 3);        // XCD-chunked, bijective
  const int m0 = (swz >> 4) * 128, n0 = (swz & 15) * 64;
  const int wid = tid >> 6, lane = tid & 63;
  const int lr = lane & 15, lg = lane >> 4;

  f32x4 acc[2][4] = {};
  const int T = K >> 6;

  for (int t = 0; t < T; ++t) {
    const int k0 = t << 6;
    __syncthreads();
    #pragma unroll
    for (int j = 0; j < 4; ++j) {
      const int c = j * 256 + tid;
      const int row = c >> 3;
      const int ck = (c & 7) ^ (row & 7);
      gload16(A + (size_t)(m0 + row) * K + k0 + ck * 8,
              &As[(j * 256 + (tid & 192)) * 8]);
    }
    #pragma unroll
    for (int j = 0; j < 2; ++j) {
      const int c = j * 256 + tid;
      const int row = c >> 3;
      const int ck = (c & 7) ^ (row & 7);
      gload16(B + (size_t)(n0 + row) * K + k0 + ck * 8,
              &Bs[(j * 256 + (tid & 192)) * 8]);
    }
    asm volatile("s_waitcnt vmcnt(0)" ::: "memory");
    __syncthreads();
    s16x8 af[2][2], bf[4][2];
    #pragma unroll
    for (int m = 0; m < 2; ++m)
      #pragma unroll
      for (int kk = 0; kk < 2; ++kk) {
        int row = wid * 32 + m * 16 + lr;
        af[m][kk] = *(const s16x8*)&As[row * 64 + ((kk * 32 + lg * 8) ^ ((row & 7) << 3))];
      }
    #pragma unroll
    for (int n = 0; n < 4; ++n)
      #pragma unroll
      for (int kk = 0; kk < 2; ++kk) {
        int row = n * 16 + lr;
        bf[n][kk] = *(const s16x8*)&Bs[row * 64 + ((kk * 32 + lg * 8) ^ ((row & 7) << 3))];
      }
    #pragma unroll
    for (int kk = 0; kk < 2; ++kk)
      #pragma unroll
      for (int m = 0; m < 2; ++m)
        #pragma unroll
        for (int n = 0; n < 4; ++n)
          acc[m][n] = mfma16x16(af[m][kk], bf[n][kk], acc[m][n]);
  }

  #pragma unroll
  for (int m = 0; m < 2; ++m)
    #pragma unroll
    for (int i = 0; i < 4; ++i) {
      int r = m0 + wid * 32 + m * 16 + lg * 4 + i;
      #pragma unroll
      for (int n = 0; n < 4; ++n)
        Cf[(size_t)r * N + n0 + n * 16 + lr] = acc[m][n][i];
    }
}

// ---------------------------------------------------------------------------
// Causal flash attention — r13 BODY unchanged (passing since r9); schedule
// changed: single q-tile per block, 1024 blocks = 4 blocks/CU = 16 waves/CU
// (was 2 blocks/CU = 8 waves). Per-CU work uniform by construction under the
// r10-confirmed dispatcher (chunk c -> CU c mod 32): CU slot g gets qt in
// {g, 31-g, (g+16)&31, 31-((g+16)&31)} -> exactly 66 iters for every g.
// 4-wave blocks, max-free softmax (exact), zero-shuffle PV via sigma K-row
// staging permutation. LDS 32KB/block x 4 = 128KB/CU.
// Qr/Kr: bf16 [BH][S][64] (Q pre-scaled by log2e/8), VT: bf16 [BH][64][S].
// ---------------------------------------------------------------------------
__global__ __launch_bounds__(256, 4) void attn_fwd(
    const unsigned short* __restrict__ Qr, const unsigned short* __restrict__ Kr,
    const unsigned short* __restrict__ VT, unsigned short* __restrict__ Z) {
  __shared__ __align__(16) unsigned short Kl[2][64 * 64];
  __shared__ __align__(16) unsigned short Vl[2][64 * 64];
  const int tid = threadIdx.x;
  const int orig = blockIdx.x;
  const int bid = (orig & 7) * 128 + (orig >> 3);   // XCD-chunked, bijective
  const int xcd = bid >> 7;
  const int hh = (bid >> 5) & 3;                    // head slot within XCD
  const int gg = bid & 31;                          // CU slot within XCD
  const int bh = xcd * 4 + hh;
  const int uu = (gg + ((hh >> 1) << 4)) & 31;
  const int qt = (hh & 1) ? (31 - uu) : uu;         // complementary pairs/CU
  const int b = bh >> 4, h = bh & 15;
  const int wid = tid >> 6, lane = tid & 63;
  const int lr = lane & 15, lg = lane >> 4;

  const unsigned short* Qb = Qr + ((size_t)bh << 17);
  const unsigned short* Kb = Kr + ((size_t)bh << 17);
  const unsigned short* Vb = VT + ((size_t)bh << 17);

  // staging: unit u = j*256 + tid covers row u>>3 (0..63), chunk u&7
  auto STAGE = [&](int buf, int t2) {
    const int kv = t2 << 6;
    #pragma unroll
    for (int j = 0; j < 2; ++j) {
      const int u = j * 256 + tid;
      const int row = u >> 3, ck0 = u & 7;
      const int ck = ck0 ^ (row & 7);               // pre-swizzled source chunk
      const int sig = ((row >> 4) & 1) * 32 + ((row >> 2) & 3) * 8 +
                      ((row >> 5) & 1) * 4 + (row & 3);
      gload16(Kb + (size_t)(kv + sig) * 64 + ck * 8,
              &Kl[buf][(j * 256 + (tid & 192)) * 8]);
      gload16(Vb + (size_t)row * 2048 + kv + ck * 8,
              &Vl[buf][(j * 256 + (tid & 192)) * 8]);
    }
  };

  const int qbase = qt << 6;
  const int qw = qbase + wid * 16;        // wave's first q row
  const int qabs = qw + lr;               // THE q-row this lane owns
  const int nt = qt + 1;                  // KV tiles 0..qt

  s16x8 qf[2];
  #pragma unroll
  for (int kk = 0; kk < 2; ++kk)
    qf[kk] = ld8(Qb + (size_t)(qw + lr) * 64 + kk * 32 + lg * 8);

  f32x4 oacc[4] = {};                     // O^T[d = n*16+lg*4+i][q = lr]
  float lrun = 0.f;                       // per-lane partial (reduced at end)

  STAGE(0, 0);
  asm volatile("s_waitcnt vmcnt(0)" ::: "memory");
  __syncthreads();
  int cur = 0;

  for (int t = 0; t < nt; ++t) {
    const int kv0 = t << 6;
    if (t + 1 < nt) STAGE(cur ^ 1, t + 1);   // overlaps all compute below

    // S^T = K Q^T (swapped operands, sigma-permuted K rows)
    f32x4 sacc[4] = {};
    __builtin_amdgcn_s_setprio(1);
    #pragma unroll
    for (int kk = 0; kk < 2; ++kk) {
      s16x8 kf[4];
      #pragma unroll
      for (int n = 0; n < 4; ++n) {
        const int row = n * 16 + lr;
        kf[n] = *(const s16x8*)&Kl[cur][row * 64 + ((kk * 32 + lg * 8) ^ ((row & 7) << 3))];
      }
      #pragma unroll
      for (int n = 0; n < 4; ++n)
        sacc[n] = mfma16x16(kf[n], qf[kk], sacc[n]);
    }
    __builtin_amdgcn_s_setprio(0);

    // V fragments (independent of softmax)
    s16x8 vf[2][4];
    #pragma unroll
    for (int kk = 0; kk < 2; ++kk)
      #pragma unroll
      for (int n = 0; n < 4; ++n) {
        const int row = n * 16 + lr;
        vf[kk][n] = *(const s16x8*)&Vl[cur][row * 64 + ((kk * 32 + lg * 8) ^ ((row & 7) << 3))];
      }

    // causal mask (diagonal tile only), sigma-mapped k per slot
    if (t == nt - 1) {
      #pragma unroll
      for (int n = 0; n < 4; ++n)
        #pragma unroll
        for (int i = 0; i < 4; ++i)
          if (kv0 + (n & 1) * 32 + lg * 8 + ((n >> 1) << 2) + i > qabs)
            sacc[n][i] = -__builtin_inff();
    }

    // e = exp2(S) (no max subtraction), P-frags built IN REGISTERS
    float e[4][4];
    #pragma unroll
    for (int n = 0; n < 4; ++n)
      #pragma unroll
      for (int i = 0; i < 4; ++i)
        e[n][i] = __builtin_amdgcn_exp2f(sacc[n][i]);
    u32x4 u0, u1;
    u0[0] = cvtpk(e[0][0], e[0][1]); u0[1] = cvtpk(e[0][2], e[0][3]);
    u0[2] = cvtpk(e[2][0], e[2][1]); u0[3] = cvtpk(e[2][2], e[2][3]);
    u1[0] = cvtpk(e[1][0], e[1][1]); u1[1] = cvtpk(e[1][2], e[1][3]);
    u1[2] = cvtpk(e[3][0], e[3][1]); u1[3] = cvtpk(e[3][2], e[3][3]);
    s16x8 pf0 = __builtin_bit_cast(s16x8, u0);
    s16x8 pf1 = __builtin_bit_cast(s16x8, u1);

    // off-chain: per-lane partial row sum (no shuffles in the loop)
    #pragma unroll
    for (int n = 0; n < 4; ++n)
      lrun += (e[n][0] + e[n][1]) + (e[n][2] + e[n][3]);

    // O^T += V^T P^T : zero-shuffle PV, P straight from registers
    __builtin_amdgcn_s_setprio(1);
    #pragma unroll
    for (int n = 0; n < 4; ++n)
      oacc[n] = mfma16x16(vf[0][n], pf0, oacc[n]);
    #pragma unroll
    for (int n = 0; n < 4; ++n)
      oacc[n] = mfma16x16(vf[1][n], pf1, oacc[n]);
    __builtin_amdgcn_s_setprio(0);

    // next tile's loads done + everyone finished reading buf cur
    asm volatile("s_waitcnt vmcnt(0)" ::: "memory");
    __syncthreads();
    cur ^= 1;
  }

  // final row-sum reduce across the 4 lanes sharing q, then normalize
  float ltot = lrun;
  ltot += __shfl_xor(ltot, 16);
  ltot += __shfl_xor(ltot, 32);
  const float inv = 1.f / ltot;
  const size_t base = ((size_t)b * 2048 + qabs) * 1024 + h * 64;
  #pragma unroll
  for (int n = 0; n < 4; ++n) {
    uint2 u;
    u.x = cvtpk(oacc[n][0] * inv, oacc[n][1] * inv);
    u.y = cvtpk(oacc[n][2] * inv, oacc[n][3] * inv);
    *(uint2*)&Z[base + n * 16 + lg * 4] = u;
  }
}

// ---------------------------------------------------------------------------
extern "C" void kernel_launch(void* const* d_in, const int* in_sizes, int n_in,
                              void* d_out, int out_size, void* d_ws, size_t ws_size,
                              hipStream_t stream) {
  const float* x     = (const float*)d_in[0];   // [2,2048,1024]
  const float* w_qkv = (const float*)d_in[1];   // [3072,1024]
  const float* w_o   = (const float*)d_in[2];   // [1024,1024]
  float* out = (float*)d_out;                   // [2,2048,1024] fp32

  unsigned short* wsp = (unsigned short*)d_ws;
  unsigned short* Qr  = wsp;                    // [32][2048][64] bf16  (8 MB)
  unsigned short* Kr  = wsp + 4194304;          // [32][2048][64] bf16  (8 MB)
  unsigned short* VT  = wsp + 8388608;          // [32][64][2048] bf16  (8 MB)
  unsigned short* Xb  = wsp + 12582912;         // [4096][1024]  bf16   (8 MB)
  unsigned short* Z   = Xb;                     // aliases Xb (disjoint lifetime)
  unsigned short* Wb  = wsp + 16777216;         // [3072][1024]  bf16   (6 MB)
  unsigned short* Wob = wsp + 19922944;         // [1024][1024]  bf16   (2 MB)
  // total ws use: 40 MiB

  // 0) fused one-time fp32 -> bf16 conversions
  cvt_all<<<4096, 256, 0, stream>>>(x, w_qkv, w_o, Xb, Wb, Wob);

  // 1) QKV projection (global_load_lds staging, 3 blocks/CU) + RoPE epilogue
  gemm_qkv<<<dim3(24, 32), 256, 0, stream>>>(
      Xb, Wb, Qr, Kr, VT, 4096, 3072, 1024);

  // 2) causal flash attention (single-tile blocks, CU-balanced, 4 blocks/CU)
  attn_fwd<<<1024, 256, 0, stream>>>(Qr, Kr, VT, Z);

  // 3) output projection (128x64 tiles, 2 blocks/CU) (fp32 out)
  gemm_out<<<dim3(16, 32), 256, 0, stream>>>(
      Z, Wob, out, 4096, 1024, 1024);
}

// Round 16
// 96.456 us; speedup vs baseline: 1.2289x; 1.0315x over previous
//
#include <hip/hip_runtime.h>
#include <hip/hip_bf16.h>
#include <cstdint>
#include <cstddef>

#define DEVI static __device__ __forceinline__

typedef short s16x8 __attribute__((ext_vector_type(8)));
typedef float f32x4 __attribute__((ext_vector_type(4)));
typedef unsigned u32x4 __attribute__((ext_vector_type(4)));

DEVI f32x4 mfma16x16(s16x8 a, s16x8 b, f32x4 c) {
  return __builtin_amdgcn_mfma_f32_16x16x32_bf16(a, b, c, 0, 0, 0);
}

// HW float->bf16
DEVI unsigned short hcvt(float f) {
  return __builtin_bit_cast(unsigned short, __float2bfloat16(f));
}
// packed cvt: dst[15:0]=bf16(a), dst[31:16]=bf16(b)
DEVI unsigned cvtpk(float a, float b) {
  unsigned r;
  asm("v_cvt_pk_bf16_f32 %0, %1, %2" : "=v"(r) : "v"(a), "v"(b));
  return r;
}

DEVI s16x8 ld8(const unsigned short* p) { return *(const s16x8*)p; }

// async global->LDS, 16B per lane; dest = wave-uniform base + lane*16
DEVI void gload16(const void* g, void* l) {
  __builtin_amdgcn_global_load_lds(
      (const __attribute__((address_space(1))) void*)g,
      (__attribute__((address_space(3))) void*)l, 16, 0, 0);
}

// ---------------------------------------------------------------------------
// fused fp32 -> bf16 bulk convert of all three inputs (one launch)
// ---------------------------------------------------------------------------
__global__ __launch_bounds__(256) void cvt_all(
    const float* __restrict__ x, const float* __restrict__ w1,
    const float* __restrict__ w2, unsigned short* __restrict__ Xb,
    unsigned short* __restrict__ Wb, unsigned short* __restrict__ Wob) {
  int i = blockIdx.x * 256 + threadIdx.x;   // [0, 1048576)
  const float* s;
  unsigned short* d;
  int off;
  if (i < 524288) { s = x; d = Xb; off = i; }
  else if (i < 917504) { s = w1; d = Wb; off = i - 524288; }
  else { s = w2; d = Wob; off = i - 917504; }
  const float4* sp = (const float4*)s + (size_t)off * 2;
  float4 a = sp[0], b = sp[1];
  s16x8 r;
  r[0] = (short)hcvt(a.x); r[1] = (short)hcvt(a.y);
  r[2] = (short)hcvt(a.z); r[3] = (short)hcvt(a.w);
  r[4] = (short)hcvt(b.x); r[5] = (short)hcvt(b.y);
  r[6] = (short)hcvt(b.z); r[7] = (short)hcvt(b.w);
  *(s16x8*)(d + (size_t)off * 8) = r;
}

// ---------------------------------------------------------------------------
// GEMM1: C[m][n] = sum_k A[m][k]*B[n][k], 128x128x64 tiles, global_load_lds
// staging (m97 loop, pre-swizzled source chunk), fused qkv/RoPE epilogue.
// XCD-chunked block swizzle; 3 blocks/CU (one dispatch round for 768 blocks).
// ---------------------------------------------------------------------------
__global__ __launch_bounds__(256, 3) void gemm_qkv(
    const unsigned short* __restrict__ A, const unsigned short* __restrict__ B,
    unsigned short* __restrict__ Qp, unsigned short* __restrict__ Kp,
    unsigned short* __restrict__ Vp, int M, int N, int K) {
  __shared__ __align__(16) unsigned short As[128 * 64];
  __shared__ __align__(16) unsigned short Bs[128 * 64];
  const int tid = threadIdx.x;
  const int lin = blockIdx.y * 24 + blockIdx.x;       // 0..767
  const int swz = (lin & 7) * 96 + (lin >> 3);        // XCD-chunked, bijective
  const int m0 = (swz / 24) * 128, n0 = (swz % 24) * 128;
  const int wid = tid >> 6, lane = tid & 63;
  const int wm = wid >> 1, wn = wid & 1;
  const int lr = lane & 15, lg = lane >> 4;

  f32x4 acc[4][4] = {};
  const int T = K >> 6;

  for (int t = 0; t < T; ++t) {
    const int k0 = t << 6;
    __syncthreads();
    #pragma unroll
    for (int j = 0; j < 4; ++j) {
      const int c = j * 256 + tid;
      const int row = c >> 3;
      const int ck = (c & 7) ^ (row & 7);
      gload16(A + (size_t)(m0 + row) * K + k0 + ck * 8,
              &As[(j * 256 + (tid & 192)) * 8]);
      gload16(B + (size_t)(n0 + row) * K + k0 + ck * 8,
              &Bs[(j * 256 + (tid & 192)) * 8]);
    }
    asm volatile("s_waitcnt vmcnt(0)" ::: "memory");
    __syncthreads();
    s16x8 af[4][2], bf[4][2];
    #pragma unroll
    for (int m = 0; m < 4; ++m)
      #pragma unroll
      for (int kk = 0; kk < 2; ++kk) {
        int row = wm * 64 + m * 16 + lr;
        af[m][kk] = *(const s16x8*)&As[row * 64 + ((kk * 32 + lg * 8) ^ ((row & 7) << 3))];
      }
    #pragma unroll
    for (int n = 0; n < 4; ++n)
      #pragma unroll
      for (int kk = 0; kk < 2; ++kk) {
        int row = wn * 64 + n * 16 + lr;
        bf[n][kk] = *(const s16x8*)&Bs[row * 64 + ((kk * 32 + lg * 8) ^ ((row & 7) << 3))];
      }
    #pragma unroll
    for (int kk = 0; kk < 2; ++kk)
      #pragma unroll
      for (int m = 0; m < 4; ++m)
        #pragma unroll
        for (int n = 0; n < 4; ++n)
          acc[m][n] = mfma16x16(af[m][kk], bf[n][kk], acc[m][n]);
  }

  // fused qkv split + RoPE epilogue (C/D layout: row = lg*4+i, col = lr)
  const int colb = n0 + wn * 64;          // wave's 64-col span = one head
  const int part = colb >> 10;            // 0=q 1=k 2=v (block-uniform)
  const int h = (colb & 1023) >> 6;
  #pragma unroll
  for (int m = 0; m < 4; ++m)
    #pragma unroll
    for (int i = 0; i < 4; ++i) {
      const int r = m0 + wm * 64 + m * 16 + lg * 4 + i;
      const int b = r >> 11, s = r & 2047;
      const size_t bh = (size_t)b * 16 + h;
      if (part == 2) {
        #pragma unroll
        for (int n = 0; n < 4; ++n)
          Vp[(bh * 64 + n * 16 + lr) * 2048 + s] = hcvt(acc[m][n][i]);
      } else {
        #pragma unroll
        for (int n = 0; n < 2; ++n) {
          const int d = n * 16 + lr;      // 0..31; pair (d, d+32) in-lane
          float ang = (float)s * exp2f((float)d * -0.4152410118609203f);
          float c = __cosf(ang), sn = __sinf(ang);
          float x1 = acc[m][n][i], x2 = acc[m][n + 2][i];
          float o1 = x1 * c - x2 * sn;
          float o2 = x2 * c + x1 * sn;
          unsigned short* dst;
          if (part == 0) {
            // fold 1/sqrt(dh) AND log2(e) so attention can use exp2
            o1 *= 0.18033688f; o2 *= 0.18033688f; dst = Qp;
          } else dst = Kp;
          dst[(bh * 2048 + s) * 64 + d] = hcvt(o1);
          dst[(bh * 2048 + s) * 64 + d + 32] = hcvt(o2);
        }
      }
    }
}

// ---------------------------------------------------------------------------
// GEMM3: 128x64 tiles (2 blocks/CU), global_load_lds staging, fp32 out.
// ---------------------------------------------------------------------------
__global__ __launch_bounds__(256, 2) void gemm_out(
    const unsigned short* __restrict__ A, const unsigned short* __restrict__ B,
    float* __restrict__ Cf, int M, int N, int K) {
  __shared__ __align__(16) unsigned short As[128 * 64];
  __shared__ __align__(16) unsigned short Bs[64 * 64];
  const int tid = threadIdx.x;
  const int lin = blockIdx.y * 16 + blockIdx.x;       // 0..511
  const int swz = (lin & 7) * 64 + (lin >> 3);        // XCD-chunked, bijective
  const int m0 = (swz >> 4) * 128, n0 = (swz & 15) * 64;
  const int wid = tid >> 6, lane = tid & 63;
  const int lr = lane & 15, lg = lane >> 4;

  f32x4 acc[2][4] = {};
  const int T = K >> 6;

  for (int t = 0; t < T; ++t) {
    const int k0 = t << 6;
    __syncthreads();
    #pragma unroll
    for (int j = 0; j < 4; ++j) {
      const int c = j * 256 + tid;
      const int row = c >> 3;
      const int ck = (c & 7) ^ (row & 7);
      gload16(A + (size_t)(m0 + row) * K + k0 + ck * 8,
              &As[(j * 256 + (tid & 192)) * 8]);
    }
    #pragma unroll
    for (int j = 0; j < 2; ++j) {
      const int c = j * 256 + tid;
      const int row = c >> 3;
      const int ck = (c & 7) ^ (row & 7);
      gload16(B + (size_t)(n0 + row) * K + k0 + ck * 8,
              &Bs[(j * 256 + (tid & 192)) * 8]);
    }
    asm volatile("s_waitcnt vmcnt(0)" ::: "memory");
    __syncthreads();
    s16x8 af[2][2], bf[4][2];
    #pragma unroll
    for (int m = 0; m < 2; ++m)
      #pragma unroll
      for (int kk = 0; kk < 2; ++kk) {
        int row = wid * 32 + m * 16 + lr;
        af[m][kk] = *(const s16x8*)&As[row * 64 + ((kk * 32 + lg * 8) ^ ((row & 7) << 3))];
      }
    #pragma unroll
    for (int n = 0; n < 4; ++n)
      #pragma unroll
      for (int kk = 0; kk < 2; ++kk) {
        int row = n * 16 + lr;
        bf[n][kk] = *(const s16x8*)&Bs[row * 64 + ((kk * 32 + lg * 8) ^ ((row & 7) << 3))];
      }
    #pragma unroll
    for (int kk = 0; kk < 2; ++kk)
      #pragma unroll
      for (int m = 0; m < 2; ++m)
        #pragma unroll
        for (int n = 0; n < 4; ++n)
          acc[m][n] = mfma16x16(af[m][kk], bf[n][kk], acc[m][n]);
  }

  #pragma unroll
  for (int m = 0; m < 2; ++m)
    #pragma unroll
    for (int i = 0; i < 4; ++i) {
      int r = m0 + wid * 32 + m * 16 + lg * 4 + i;
      #pragma unroll
      for (int n = 0; n < 4; ++n)
        Cf[(size_t)r * N + n0 + n * 16 + lr] = acc[m][n][i];
    }
}

// ---------------------------------------------------------------------------
// Causal flash attention — r13/r9-verified configuration (best passing).
// 4-wave blocks, max-free softmax, zero-shuffle PV.
// Block: 4 waves x 16 q-rows = 64-row q-tile; pair (p, 31-p) -> exactly 33
// KV-tile iterations; 512 blocks (XCD-chunked) = 2 blocks/CU, 8 waves/CU.
// KV staged via dbuf global_load_lds. Softmax MAX-FREE (exact: softmax is
// scale-invariant; exp2<=2^10, lrun<=2^21 in fp32 range). K rows
// sigma-permuted at the staging source so QK C-slot == PV B-slot.
// ---------------------------------------------------------------------------
__global__ __launch_bounds__(256, 2) void attn_fwd(
    const unsigned short* __restrict__ Qr, const unsigned short* __restrict__ Kr,
    const unsigned short* __restrict__ VT, unsigned short* __restrict__ Z) {
  __shared__ __align__(16) unsigned short Kl[2][64 * 64];
  __shared__ __align__(16) unsigned short Vl[2][64 * 64];
  const int tid = threadIdx.x;
  const int orig = blockIdx.x;
  const int bid = (orig & 7) * 64 + (orig >> 3);    // XCD-chunked, bijective
  const int bh = bid >> 4, p = bid & 15;
  const int b = bh >> 4, h = bh & 15;
  const int wid = tid >> 6, lane = tid & 63;
  const int lr = lane & 15, lg = lane >> 4;

  const unsigned short* Qb = Qr + ((size_t)bh << 17);
  const unsigned short* Kb = Kr + ((size_t)bh << 17);
  const unsigned short* Vb = VT + ((size_t)bh << 17);

  // staging: unit u = j*256 + tid covers row u>>3 (0..63), chunk u&7
  auto STAGE = [&](int buf, int t2) {
    const int kv = t2 << 6;
    #pragma unroll
    for (int j = 0; j < 2; ++j) {
      const int u = j * 256 + tid;
      const int row = u >> 3, ck0 = u & 7;
      const int ck = ck0 ^ (row & 7);               // pre-swizzled source chunk
      const int sig = ((row >> 4) & 1) * 32 + ((row >> 2) & 3) * 8 +
                      ((row >> 5) & 1) * 4 + (row & 3);
      gload16(Kb + (size_t)(kv + sig) * 64 + ck * 8,
              &Kl[buf][(j * 256 + (tid & 192)) * 8]);
      gload16(Vb + (size_t)row * 2048 + kv + ck * 8,
              &Vl[buf][(j * 256 + (tid & 192)) * 8]);
    }
  };

  #pragma unroll
  for (int side = 0; side < 2; ++side) {
    const int qt = side ? (31 - p) : p;     // 64-row q-tile index
    const int qbase = qt << 6;
    const int qw = qbase + wid * 16;        // wave's first q row
    const int qabs = qw + lr;               // THE q-row this lane owns
    const int nt = qt + 1;                  // KV tiles 0..qt

    s16x8 qf[2];
    #pragma unroll
    for (int kk = 0; kk < 2; ++kk)
      qf[kk] = ld8(Qb + (size_t)(qw + lr) * 64 + kk * 32 + lg * 8);

    f32x4 oacc[4] = {};                     // O^T[d = n*16+lg*4+i][q = lr]
    float lrun = 0.f;                       // per-lane partial (reduced at end)

    STAGE(0, 0);
    asm volatile("s_waitcnt vmcnt(0)" ::: "memory");
    __syncthreads();
    int cur = 0;

    for (int t = 0; t < nt; ++t) {
      const int kv0 = t << 6;
      if (t + 1 < nt) STAGE(cur ^ 1, t + 1);   // overlaps all compute below

      // S^T = K Q^T (swapped operands, sigma-permuted K rows)
      f32x4 sacc[4] = {};
      __builtin_amdgcn_s_setprio(1);
      #pragma unroll
      for (int kk = 0; kk < 2; ++kk) {
        s16x8 kf[4];
        #pragma unroll
        for (int n = 0; n < 4; ++n) {
          const int row = n * 16 + lr;
          kf[n] = *(const s16x8*)&Kl[cur][row * 64 + ((kk * 32 + lg * 8) ^ ((row & 7) << 3))];
        }
        #pragma unroll
        for (int n = 0; n < 4; ++n)
          sacc[n] = mfma16x16(kf[n], qf[kk], sacc[n]);
      }
      __builtin_amdgcn_s_setprio(0);

      // V fragments (independent of softmax)
      s16x8 vf[2][4];
      #pragma unroll
      for (int kk = 0; kk < 2; ++kk)
        #pragma unroll
        for (int n = 0; n < 4; ++n) {
          const int row = n * 16 + lr;
          vf[kk][n] = *(const s16x8*)&Vl[cur][row * 64 + ((kk * 32 + lg * 8) ^ ((row & 7) << 3))];
        }

      // causal mask (diagonal tile only), sigma-mapped k per slot
      if (t == nt - 1) {
        #pragma unroll
        for (int n = 0; n < 4; ++n)
          #pragma unroll
          for (int i = 0; i < 4; ++i)
            if (kv0 + (n & 1) * 32 + lg * 8 + ((n >> 1) << 2) + i > qabs)
              sacc[n][i] = -__builtin_inff();
      }

      // e = exp2(S) (no max subtraction), P-frags built IN REGISTERS
      float e[4][4];
      #pragma unroll
      for (int n = 0; n < 4; ++n)
        #pragma unroll
        for (int i = 0; i < 4; ++i)
          e[n][i] = __builtin_amdgcn_exp2f(sacc[n][i]);
      u32x4 u0, u1;
      u0[0] = cvtpk(e[0][0], e[0][1]); u0[1] = cvtpk(e[0][2], e[0][3]);
      u0[2] = cvtpk(e[2][0], e[2][1]); u0[3] = cvtpk(e[2][2], e[2][3]);
      u1[0] = cvtpk(e[1][0], e[1][1]); u1[1] = cvtpk(e[1][2], e[1][3]);
      u1[2] = cvtpk(e[3][0], e[3][1]); u1[3] = cvtpk(e[3][2], e[3][3]);
      s16x8 pf0 = __builtin_bit_cast(s16x8, u0);
      s16x8 pf1 = __builtin_bit_cast(s16x8, u1);

      // off-chain: per-lane partial row sum (no shuffles in the loop)
      #pragma unroll
      for (int n = 0; n < 4; ++n)
        lrun += (e[n][0] + e[n][1]) + (e[n][2] + e[n][3]);

      // O^T += V^T P^T : zero-shuffle PV, P straight from registers
      __builtin_amdgcn_s_setprio(1);
      #pragma unroll
      for (int n = 0; n < 4; ++n)
        oacc[n] = mfma16x16(vf[0][n], pf0, oacc[n]);
      #pragma unroll
      for (int n = 0; n < 4; ++n)
        oacc[n] = mfma16x16(vf[1][n], pf1, oacc[n]);
      __builtin_amdgcn_s_setprio(0);

      // next tile's loads done + everyone finished reading buf cur
      asm volatile("s_waitcnt vmcnt(0)" ::: "memory");
      __syncthreads();
      cur ^= 1;
    }

    // final row-sum reduce across the 4 lanes sharing q, then normalize
    float ltot = lrun;
    ltot += __shfl_xor(ltot, 16);
    ltot += __shfl_xor(ltot, 32);
    const float inv = 1.f / ltot;
    const size_t base = ((size_t)b * 2048 + qabs) * 1024 + h * 64;
    #pragma unroll
    for (int n = 0; n < 4; ++n) {
      uint2 u;
      u.x = cvtpk(oacc[n][0] * inv, oacc[n][1] * inv);
      u.y = cvtpk(oacc[n][2] * inv, oacc[n][3] * inv);
      *(uint2*)&Z[base + n * 16 + lg * 4] = u;
    }
  }
}

// ---------------------------------------------------------------------------
extern "C" void kernel_launch(void* const* d_in, const int* in_sizes, int n_in,
                              void* d_out, int out_size, void* d_ws, size_t ws_size,
                              hipStream_t stream) {
  const float* x     = (const float*)d_in[0];   // [2,2048,1024]
  const float* w_qkv = (const float*)d_in[1];   // [3072,1024]
  const float* w_o   = (const float*)d_in[2];   // [1024,1024]
  float* out = (float*)d_out;                   // [2,2048,1024] fp32

  unsigned short* wsp = (unsigned short*)d_ws;
  unsigned short* Qr  = wsp;                    // [32][2048][64] bf16  (8 MB)
  unsigned short* Kr  = wsp + 4194304;          // [32][2048][64] bf16  (8 MB)
  unsigned short* VT  = wsp + 8388608;          // [32][64][2048] bf16  (8 MB)
  unsigned short* Xb  = wsp + 12582912;         // [4096][1024]  bf16   (8 MB)
  unsigned short* Z   = Xb;                     // aliases Xb (disjoint lifetime)
  unsigned short* Wb  = wsp + 16777216;         // [3072][1024]  bf16   (6 MB)
  unsigned short* Wob = wsp + 19922944;         // [1024][1024]  bf16   (2 MB)
  // total ws use: 40 MiB

  // 0) fused one-time fp32 -> bf16 conversions
  cvt_all<<<4096, 256, 0, stream>>>(x, w_qkv, w_o, Xb, Wb, Wob);

  // 1) QKV projection (global_load_lds staging, 3 blocks/CU) + RoPE epilogue
  gemm_qkv<<<dim3(24, 32), 256, 0, stream>>>(
      Xb, Wb, Qr, Kr, VT, 4096, 3072, 1024);

  // 2) causal flash attention (r9/r13: 4-wave pair blocks, max-free softmax)
  attn_fwd<<<512, 256, 0, stream>>>(Qr, Kr, VT, Z);

  // 3) output projection (128x64 tiles, 2 blocks/CU) (fp32 out)
  gemm_out<<<dim3(16, 32), 256, 0, stream>>>(
      Z, Wob, out, 4096, 1024, 1024);
}

// Round 17
// 94.954 us; speedup vs baseline: 1.2483x; 1.0158x over previous
//
#include <hip/hip_runtime.h>
#include <hip/hip_bf16.h>
#include <cstdint>
#include <cstddef>

#define DEVI static __device__ __forceinline__

typedef short s16x8 __attribute__((ext_vector_type(8)));
typedef float f32x4 __attribute__((ext_vector_type(4)));
typedef unsigned u32x4 __attribute__((ext_vector_type(4)));

DEVI f32x4 mfma16x16(s16x8 a, s16x8 b, f32x4 c) {
  return __builtin_amdgcn_mfma_f32_16x16x32_bf16(a, b, c, 0, 0, 0);
}

// HW float->bf16
DEVI unsigned short hcvt(float f) {
  return __builtin_bit_cast(unsigned short, __float2bfloat16(f));
}
// packed cvt: dst[15:0]=bf16(a), dst[31:16]=bf16(b)
DEVI unsigned cvtpk(float a, float b) {
  unsigned r;
  asm("v_cvt_pk_bf16_f32 %0, %1, %2" : "=v"(r) : "v"(a), "v"(b));
  return r;
}

DEVI s16x8 ld8(const unsigned short* p) { return *(const s16x8*)p; }

// async global->LDS, 16B per lane; dest = wave-uniform base + lane*16
DEVI void gload16(const void* g, void* l) {
  __builtin_amdgcn_global_load_lds(
      (const __attribute__((address_space(1))) void*)g,
      (__attribute__((address_space(3))) void*)l, 16, 0, 0);
}

// ---------------------------------------------------------------------------
// fused fp32 -> bf16 bulk convert of all three inputs (one launch)
// ---------------------------------------------------------------------------
__global__ __launch_bounds__(256) void cvt_all(
    const float* __restrict__ x, const float* __restrict__ w1,
    const float* __restrict__ w2, unsigned short* __restrict__ Xb,
    unsigned short* __restrict__ Wb, unsigned short* __restrict__ Wob) {
  int i = blockIdx.x * 256 + threadIdx.x;   // [0, 1048576)
  const float* s;
  unsigned short* d;
  int off;
  if (i < 524288) { s = x; d = Xb; off = i; }
  else if (i < 917504) { s = w1; d = Wb; off = i - 524288; }
  else { s = w2; d = Wob; off = i - 917504; }
  const float4* sp = (const float4*)s + (size_t)off * 2;
  float4 a = sp[0], b = sp[1];
  s16x8 r;
  r[0] = (short)hcvt(a.x); r[1] = (short)hcvt(a.y);
  r[2] = (short)hcvt(a.z); r[3] = (short)hcvt(a.w);
  r[4] = (short)hcvt(b.x); r[5] = (short)hcvt(b.y);
  r[6] = (short)hcvt(b.z); r[7] = (short)hcvt(b.w);
  *(s16x8*)(d + (size_t)off * 8) = r;
}

// ---------------------------------------------------------------------------
// GEMM1: C[m][n] = sum_k A[m][k]*B[n][k], 128x128x64 tiles, global_load_lds
// staging (m97 loop, pre-swizzled source chunk), fused qkv/RoPE epilogue.
// XCD-chunked block swizzle; 3 blocks/CU (one dispatch round for 768 blocks).
// ---------------------------------------------------------------------------
__global__ __launch_bounds__(256, 3) void gemm_qkv(
    const unsigned short* __restrict__ A, const unsigned short* __restrict__ B,
    unsigned short* __restrict__ Qp, unsigned short* __restrict__ Kp,
    unsigned short* __restrict__ Vp, int M, int N, int K) {
  __shared__ __align__(16) unsigned short As[128 * 64];
  __shared__ __align__(16) unsigned short Bs[128 * 64];
  const int tid = threadIdx.x;
  const int lin = blockIdx.y * 24 + blockIdx.x;       // 0..767
  const int swz = (lin & 7) * 96 + (lin >> 3);        // XCD-chunked, bijective
  const int m0 = (swz / 24) * 128, n0 = (swz % 24) * 128;
  const int wid = tid >> 6, lane = tid & 63;
  const int wm = wid >> 1, wn = wid & 1;
  const int lr = lane & 15, lg = lane >> 4;

  f32x4 acc[4][4] = {};
  const int T = K >> 6;

  for (int t = 0; t < T; ++t) {
    const int k0 = t << 6;
    __syncthreads();
    #pragma unroll
    for (int j = 0; j < 4; ++j) {
      const int c = j * 256 + tid;
      const int row = c >> 3;
      const int ck = (c & 7) ^ (row & 7);
      gload16(A + (size_t)(m0 + row) * K + k0 + ck * 8,
              &As[(j * 256 + (tid & 192)) * 8]);
      gload16(B + (size_t)(n0 + row) * K + k0 + ck * 8,
              &Bs[(j * 256 + (tid & 192)) * 8]);
    }
    asm volatile("s_waitcnt vmcnt(0)" ::: "memory");
    __syncthreads();
    s16x8 af[4][2], bf[4][2];
    #pragma unroll
    for (int m = 0; m < 4; ++m)
      #pragma unroll
      for (int kk = 0; kk < 2; ++kk) {
        int row = wm * 64 + m * 16 + lr;
        af[m][kk] = *(const s16x8*)&As[row * 64 + ((kk * 32 + lg * 8) ^ ((row & 7) << 3))];
      }
    #pragma unroll
    for (int n = 0; n < 4; ++n)
      #pragma unroll
      for (int kk = 0; kk < 2; ++kk) {
        int row = wn * 64 + n * 16 + lr;
        bf[n][kk] = *(const s16x8*)&Bs[row * 64 + ((kk * 32 + lg * 8) ^ ((row & 7) << 3))];
      }
    #pragma unroll
    for (int kk = 0; kk < 2; ++kk)
      #pragma unroll
      for (int m = 0; m < 4; ++m)
        #pragma unroll
        for (int n = 0; n < 4; ++n)
          acc[m][n] = mfma16x16(af[m][kk], bf[n][kk], acc[m][n]);
  }

  // fused qkv split + RoPE epilogue (C/D layout: row = lg*4+i, col = lr)
  const int colb = n0 + wn * 64;          // wave's 64-col span = one head
  const int part = colb >> 10;            // 0=q 1=k 2=v (block-uniform)
  const int h = (colb & 1023) >> 6;
  #pragma unroll
  for (int m = 0; m < 4; ++m)
    #pragma unroll
    for (int i = 0; i < 4; ++i) {
      const int r = m0 + wm * 64 + m * 16 + lg * 4 + i;
      const int b = r >> 11, s = r & 2047;
      const size_t bh = (size_t)b * 16 + h;
      if (part == 2) {
        #pragma unroll
        for (int n = 0; n < 4; ++n)
          Vp[(bh * 64 + n * 16 + lr) * 2048 + s] = hcvt(acc[m][n][i]);
      } else {
        #pragma unroll
        for (int n = 0; n < 2; ++n) {
          const int d = n * 16 + lr;      // 0..31; pair (d, d+32) in-lane
          float ang = (float)s * exp2f((float)d * -0.4152410118609203f);
          float c = __cosf(ang), sn = __sinf(ang);
          float x1 = acc[m][n][i], x2 = acc[m][n + 2][i];
          float o1 = x1 * c - x2 * sn;
          float o2 = x2 * c + x1 * sn;
          unsigned short* dst;
          if (part == 0) {
            // fold 1/sqrt(dh) AND log2(e) so attention can use exp2
            o1 *= 0.18033688f; o2 *= 0.18033688f; dst = Qp;
          } else dst = Kp;
          dst[(bh * 2048 + s) * 64 + d] = hcvt(o1);
          dst[(bh * 2048 + s) * 64 + d + 32] = hcvt(o2);
        }
      }
    }
}

// ---------------------------------------------------------------------------
// GEMM3: 128x64 tiles (2 blocks/CU), global_load_lds staging, fp32 out.
// ---------------------------------------------------------------------------
__global__ __launch_bounds__(256, 2) void gemm_out(
    const unsigned short* __restrict__ A, const unsigned short* __restrict__ B,
    float* __restrict__ Cf, int M, int N, int K) {
  __shared__ __align__(16) unsigned short As[128 * 64];
  __shared__ __align__(16) unsigned short Bs[64 * 64];
  const int tid = threadIdx.x;
  const int lin = blockIdx.y * 16 + blockIdx.x;       // 0..511
  const int swz = (lin & 7) * 64 + (lin >> 3);        // XCD-chunked, bijective
  const int m0 = (swz >> 4) * 128, n0 = (swz & 15) * 64;
  const int wid = tid >> 6, lane = tid & 63;
  const int lr = lane & 15, lg = lane >> 4;

  f32x4 acc[2][4] = {};
  const int T = K >> 6;

  for (int t = 0; t < T; ++t) {
    const int k0 = t << 6;
    __syncthreads();
    #pragma unroll
    for (int j = 0; j < 4; ++j) {
      const int c = j * 256 + tid;
      const int row = c >> 3;
      const int ck = (c & 7) ^ (row & 7);
      gload16(A + (size_t)(m0 + row) * K + k0 + ck * 8,
              &As[(j * 256 + (tid & 192)) * 8]);
    }
    #pragma unroll
    for (int j = 0; j < 2; ++j) {
      const int c = j * 256 + tid;
      const int row = c >> 3;
      const int ck = (c & 7) ^ (row & 7);
      gload16(B + (size_t)(n0 + row) * K + k0 + ck * 8,
              &Bs[(j * 256 + (tid & 192)) * 8]);
    }
    asm volatile("s_waitcnt vmcnt(0)" ::: "memory");
    __syncthreads();
    s16x8 af[2][2], bf[4][2];
    #pragma unroll
    for (int m = 0; m < 2; ++m)
      #pragma unroll
      for (int kk = 0; kk < 2; ++kk) {
        int row = wid * 32 + m * 16 + lr;
        af[m][kk] = *(const s16x8*)&As[row * 64 + ((kk * 32 + lg * 8) ^ ((row & 7) << 3))];
      }
    #pragma unroll
    for (int n = 0; n < 4; ++n)
      #pragma unroll
      for (int kk = 0; kk < 2; ++kk) {
        int row = n * 16 + lr;
        bf[n][kk] = *(const s16x8*)&Bs[row * 64 + ((kk * 32 + lg * 8) ^ ((row & 7) << 3))];
      }
    #pragma unroll
    for (int kk = 0; kk < 2; ++kk)
      #pragma unroll
      for (int m = 0; m < 2; ++m)
        #pragma unroll
        for (int n = 0; n < 4; ++n)
          acc[m][n] = mfma16x16(af[m][kk], bf[n][kk], acc[m][n]);
  }

  #pragma unroll
  for (int m = 0; m < 2; ++m)
    #pragma unroll
    for (int i = 0; i < 4; ++i) {
      int r = m0 + wid * 32 + m * 16 + lg * 4 + i;
      #pragma unroll
      for (int n = 0; n < 4; ++n)
        Cf[(size_t)r * N + n0 + n * 16 + lr] = acc[m][n][i];
    }
}

// ---------------------------------------------------------------------------
// Causal flash attention — r13 body with KVBLK=128: stage 128 KV rows per
// buffer, run the verified 64-row compute pass TWICE per barrier pair
// (sequential duplication, like r9's side loop — NOT the dual-accumulator
// interleave that failed in r11/r12). Barrier/drain pairs per block: 33 -> 17
// at identical LDS traffic and identical per-pass fragment addresses.
// nt = (qt>>1)+1 128-wide tiles; pair (p,31-p) -> exactly 17 iters/block for
// every p. Diagonal tile: mask both passes (below-diagonal conditions
// vacuously false); fully-beyond-diagonal 2nd pass skipped (block-uniform).
// LDS: Kl 32KB + Vl 32KB = 64KB/block, 2 blocks/CU = 128KB.
// Max-free softmax (exact), zero-shuffle PV via sigma K-row staging perm.
// Qr/Kr: bf16 [BH][S][64] (Q pre-scaled by log2e/8), VT: bf16 [BH][64][S].
// ---------------------------------------------------------------------------
__global__ __launch_bounds__(256, 2) void attn_fwd(
    const unsigned short* __restrict__ Qr, const unsigned short* __restrict__ Kr,
    const unsigned short* __restrict__ VT, unsigned short* __restrict__ Z) {
  __shared__ __align__(16) unsigned short Kl[2][128 * 64];   // [buf][half|row][64]
  __shared__ __align__(16) unsigned short Vl[2][2 * 64 * 64]; // [buf][half][d][64]
  const int tid = threadIdx.x;
  const int orig = blockIdx.x;
  const int bid = (orig & 7) * 64 + (orig >> 3);    // XCD-chunked, bijective
  const int bh = bid >> 4, p = bid & 15;
  const int b = bh >> 4, h = bh & 15;
  const int wid = tid >> 6, lane = tid & 63;
  const int lr = lane & 15, lg = lane >> 4;

  const unsigned short* Qb = Qr + ((size_t)bh << 17);
  const unsigned short* Kb = Kr + ((size_t)bh << 17);
  const unsigned short* Vb = VT + ((size_t)bh << 17);

  // stage 128 K rows (sigma within each 64-half) + V^T [2 halves][64 d][64 kv]
  // unit u = j*256 + tid -> chunk u of the 1024-chunk (16KB) destination
  auto STAGE = [&](int buf, int t2) {
    const int kv = t2 << 7;
    #pragma unroll
    for (int j = 0; j < 4; ++j) {
      const int u = j * 256 + tid;
      // K: row127 = u>>3, chunk = u&7 (pre-swizzled source)
      const int rowk = u >> 3;
      const int ckk = (u & 7) ^ (rowk & 7);
      const int r6 = rowk & 63;
      const int sig = (rowk & 64) + ((r6 >> 4) & 1) * 32 + ((r6 >> 2) & 3) * 8 +
                      ((r6 >> 5) & 1) * 4 + (r6 & 3);
      gload16(Kb + (size_t)(kv + sig) * 64 + ckk * 8,
              &Kl[buf][(j * 256 + (tid & 192)) * 8]);
      // V: half = u>>9, d-row = (u>>3)&63, chunk = u&7 (pre-swizzled source)
      const int hf = u >> 9;
      const int rv = (u >> 3) & 63;
      const int ckv = (u & 7) ^ (rv & 7);
      gload16(Vb + (size_t)rv * 2048 + kv + hf * 64 + ckv * 8,
              &Vl[buf][(j * 256 + (tid & 192)) * 8]);
    }
  };

  #pragma unroll
  for (int side = 0; side < 2; ++side) {
    const int qt = side ? (31 - p) : p;     // 64-row q-tile index
    const int qbase = qt << 6;
    const int qw = qbase + wid * 16;        // wave's first q row
    const int qabs = qw + lr;               // THE q-row this lane owns
    const int nt = (qt >> 1) + 1;           // 128-wide KV tiles

    s16x8 qf[2];
    #pragma unroll
    for (int kk = 0; kk < 2; ++kk)
      qf[kk] = ld8(Qb + (size_t)(qw + lr) * 64 + kk * 32 + lg * 8);

    f32x4 oacc[4] = {};                     // O^T[d = n*16+lg*4+i][q = lr]
    float lrun = 0.f;                       // per-lane partial (reduced at end)

    // one 64-row compute pass (the r9/r13-verified body, parameterized)
    auto PASS = [&](int kvp, const unsigned short* Kh, const unsigned short* Vh,
                    bool diag) {
      // S^T = K Q^T (swapped operands, sigma-permuted K rows)
      f32x4 sacc[4] = {};
      __builtin_amdgcn_s_setprio(1);
      #pragma unroll
      for (int kk = 0; kk < 2; ++kk) {
        s16x8 kf[4];
        #pragma unroll
        for (int n = 0; n < 4; ++n) {
          const int row = n * 16 + lr;
          kf[n] = *(const s16x8*)&Kh[row * 64 + ((kk * 32 + lg * 8) ^ ((row & 7) << 3))];
        }
        #pragma unroll
        for (int n = 0; n < 4; ++n)
          sacc[n] = mfma16x16(kf[n], qf[kk], sacc[n]);
      }
      __builtin_amdgcn_s_setprio(0);

      // V fragments (independent of softmax)
      s16x8 vf[2][4];
      #pragma unroll
      for (int kk = 0; kk < 2; ++kk)
        #pragma unroll
        for (int n = 0; n < 4; ++n) {
          const int row = n * 16 + lr;
          vf[kk][n] = *(const s16x8*)&Vh[row * 64 + ((kk * 32 + lg * 8) ^ ((row & 7) << 3))];
        }

      // causal mask (diagonal tile only), sigma-mapped k per slot
      if (diag) {
        #pragma unroll
        for (int n = 0; n < 4; ++n)
          #pragma unroll
          for (int i = 0; i < 4; ++i)
            if (kvp + (n & 1) * 32 + lg * 8 + ((n >> 1) << 2) + i > qabs)
              sacc[n][i] = -__builtin_inff();
      }

      // e = exp2(S) (no max subtraction), P-frags built IN REGISTERS
      float e[4][4];
      #pragma unroll
      for (int n = 0; n < 4; ++n)
        #pragma unroll
        for (int i = 0; i < 4; ++i)
          e[n][i] = __builtin_amdgcn_exp2f(sacc[n][i]);
      u32x4 u0, u1;
      u0[0] = cvtpk(e[0][0], e[0][1]); u0[1] = cvtpk(e[0][2], e[0][3]);
      u0[2] = cvtpk(e[2][0], e[2][1]); u0[3] = cvtpk(e[2][2], e[2][3]);
      u1[0] = cvtpk(e[1][0], e[1][1]); u1[1] = cvtpk(e[1][2], e[1][3]);
      u1[2] = cvtpk(e[3][0], e[3][1]); u1[3] = cvtpk(e[3][2], e[3][3]);
      s16x8 pf0 = __builtin_bit_cast(s16x8, u0);
      s16x8 pf1 = __builtin_bit_cast(s16x8, u1);

      // off-chain: per-lane partial row sum (no shuffles in the loop)
      #pragma unroll
      for (int n = 0; n < 4; ++n)
        lrun += (e[n][0] + e[n][1]) + (e[n][2] + e[n][3]);

      // O^T += V^T P^T : zero-shuffle PV, P straight from registers
      __builtin_amdgcn_s_setprio(1);
      #pragma unroll
      for (int n = 0; n < 4; ++n)
        oacc[n] = mfma16x16(vf[0][n], pf0, oacc[n]);
      #pragma unroll
      for (int n = 0; n < 4; ++n)
        oacc[n] = mfma16x16(vf[1][n], pf1, oacc[n]);
      __builtin_amdgcn_s_setprio(0);
    };

    STAGE(0, 0);
    asm volatile("s_waitcnt vmcnt(0)" ::: "memory");
    __syncthreads();
    int cur = 0;

    for (int t = 0; t < nt; ++t) {
      const int kv0 = t << 7;
      if (t + 1 < nt) STAGE(cur ^ 1, t + 1);   // overlaps both passes below

      const bool diag = (t == nt - 1);
      PASS(kv0, &Kl[cur][0], &Vl[cur][0], diag);
      if (kv0 + 64 <= qbase + 63)              // 2nd half not fully beyond diag
        PASS(kv0 + 64, &Kl[cur][64 * 64], &Vl[cur][64 * 64], diag);

      // next tile's loads done + everyone finished reading buf cur
      asm volatile("s_waitcnt vmcnt(0)" ::: "memory");
      __syncthreads();
      cur ^= 1;
    }

    // final row-sum reduce across the 4 lanes sharing q, then normalize
    float ltot = lrun;
    ltot += __shfl_xor(ltot, 16);
    ltot += __shfl_xor(ltot, 32);
    const float inv = 1.f / ltot;
    const size_t base = ((size_t)b * 2048 + qabs) * 1024 + h * 64;
    #pragma unroll
    for (int n = 0; n < 4; ++n) {
      uint2 u;
      u.x = cvtpk(oacc[n][0] * inv, oacc[n][1] * inv);
      u.y = cvtpk(oacc[n][2] * inv, oacc[n][3] * inv);
      *(uint2*)&Z[base + n * 16 + lg * 4] = u;
    }
  }
}

// ---------------------------------------------------------------------------
extern "C" void kernel_launch(void* const* d_in, const int* in_sizes, int n_in,
                              void* d_out, int out_size, void* d_ws, size_t ws_size,
                              hipStream_t stream) {
  const float* x     = (const float*)d_in[0];   // [2,2048,1024]
  const float* w_qkv = (const float*)d_in[1];   // [3072,1024]
  const float* w_o   = (const float*)d_in[2];   // [1024,1024]
  float* out = (float*)d_out;                   // [2,2048,1024] fp32

  unsigned short* wsp = (unsigned short*)d_ws;
  unsigned short* Qr  = wsp;                    // [32][2048][64] bf16  (8 MB)
  unsigned short* Kr  = wsp + 4194304;          // [32][2048][64] bf16  (8 MB)
  unsigned short* VT  = wsp + 8388608;          // [32][64][2048] bf16  (8 MB)
  unsigned short* Xb  = wsp + 12582912;         // [4096][1024]  bf16   (8 MB)
  unsigned short* Z   = Xb;                     // aliases Xb (disjoint lifetime)
  unsigned short* Wb  = wsp + 16777216;         // [3072][1024]  bf16   (6 MB)
  unsigned short* Wob = wsp + 19922944;         // [1024][1024]  bf16   (2 MB)
  // total ws use: 40 MiB

  // 0) fused one-time fp32 -> bf16 conversions
  cvt_all<<<4096, 256, 0, stream>>>(x, w_qkv, w_o, Xb, Wb, Wob);

  // 1) QKV projection (global_load_lds staging, 3 blocks/CU) + RoPE epilogue
  gemm_qkv<<<dim3(24, 32), 256, 0, stream>>>(
      Xb, Wb, Qr, Kr, VT, 4096, 3072, 1024);

  // 2) causal flash attention (KVBLK=128: 2 passes per barrier pair)
  attn_fwd<<<512, 256, 0, stream>>>(Qr, Kr, VT, Z);

  // 3) output projection (128x64 tiles, 2 blocks/CU) (fp32 out)
  gemm_out<<<dim3(16, 32), 256, 0, stream>>>(
      Z, Wob, out, 4096, 1024, 1024);
}